// Round 3
// baseline (582.248 us; speedup 1.0000x reference)
//
#include <hip/hip_runtime.h>
#include <hip/hip_bf16.h>

typedef __bf16 bf16;
typedef __bf16 bf16x8 __attribute__((ext_vector_type(8)));
typedef float  f32x4  __attribute__((ext_vector_type(4)));

#define S_SP 3136              // 56*56
#define SCALE_V (1.0f/896.0f)  // (56*56*256)^-0.5, exact

__device__ __forceinline__ float bf2f(bf16 x) { return (float)x; }

__device__ __forceinline__ bf16x8 load8(const float* p) {
    f32x4 a = *(const f32x4*)p;
    f32x4 b = *(const f32x4*)(p + 4);
    bf16x8 r;
    r[0] = (bf16)a[0]; r[1] = (bf16)a[1]; r[2] = (bf16)a[2]; r[3] = (bf16)a[3];
    r[4] = (bf16)b[0]; r[5] = (bf16)b[1]; r[6] = (bf16)b[2]; r[7] = (bf16)b[3];
    return r;
}
__device__ __forceinline__ bf16x8 load8(const bf16* p) { return *(const bf16x8*)p; }

// ---------------------------------------------------------------------------
// Transpose per batch: in [b][C][3136] (f32 or bf16) -> out [b][3136][C] bf16.
// 64x64 tiles, LDS bounce. grid (49, C/64, 16), 256 threads.
// ---------------------------------------------------------------------------
template<typename TI>
__global__ __launch_bounds__(256)
void transpose_kernel(const TI* __restrict__ in, bf16* __restrict__ out, int C)
{
    __shared__ bf16 T[64][72];
    const int s0 = blockIdx.x * 64, c0 = blockIdx.y * 64, b = blockIdx.z;
    const int tid = threadIdx.x;
    const TI* ib = in + (size_t)b * C * S_SP;
    bf16* ob = out + (size_t)b * S_SP * C;
    {
        int sx = (tid & 7) * 8, cy = tid >> 3;   // cy 0..31
        #pragma unroll
        for (int i = 0; i < 2; ++i) {
            int cl = cy + i * 32;
            bf16x8 v = load8(ib + (size_t)(c0 + cl) * S_SP + s0 + sx);
            *(bf16x8*)&T[cl][sx] = v;
        }
    }
    __syncthreads();
    #pragma unroll
    for (int i = 0; i < 2; ++i) {
        int task = tid + i * 256;
        int sl = task & 63, c8 = (task >> 6) * 8;
        bf16x8 v;
        #pragma unroll
        for (int u = 0; u < 8; ++u) v[u] = T[c8 + u][sl];   // stride-72 rows, lanes along sl: conflict-free
        *(bf16x8*)(ob + (size_t)(s0 + sl) * C + c0 + c8) = v;
    }
}

// ---------------------------------------------------------------------------
// Weight prep: f32 -> bf16, concatenated. grid (256, 7).
// layout (elems): la_w1@0(16384) la_w2@16384(16384) lk@32768 lv@98304
//                 gk@163840 gv@229376 c1@294912 (65536 each)
// ---------------------------------------------------------------------------
__global__ __launch_bounds__(256)
void wprep_kernel(const float* s0, const float* s1, const float* s2,
                  const float* s3, const float* s4, const float* s5,
                  const float* s6, bf16* __restrict__ dst)
{
    const int sizes[7] = {16384,16384,65536,65536,65536,65536,65536};
    const int offs[7]  = {0,16384,32768,98304,163840,229376,294912};
    int seg = blockIdx.y;
    const float* src = seg==0?s0:seg==1?s1:seg==2?s2:seg==3?s3:seg==4?s4:seg==5?s5:s6;
    int idx = blockIdx.x * 256 + threadIdx.x;
    if (idx < sizes[seg]) dst[offs[seg] + idx] = (bf16)src[idx];
}

// ---------------------------------------------------------------------------
// LDS-free conv1x1 GEMM: D[m=o][n=s] = sum_c W[o][c] * XT[s][c].
// Both fragments k(c)-contiguous in global -> direct dwordx4 loads, no LDS,
// no barriers; L1/L2 provide reuse. 4 waves arranged WMxWN, wave tile 64x64.
// grid (ceil(3136/(64*WN)), O/(64*WM), 16).
// ---------------------------------------------------------------------------
template<int CIN, int WM, int WN, bool LRELU, bool BN_, bool PAD_OUT, typename TY>
__global__ __launch_bounds__(256)
void conv_nolds(const bf16* __restrict__ XT, const bf16* __restrict__ Wb,
                const float* __restrict__ blo, const float* __restrict__ bhi,
                const float* __restrict__ bng, const float* __restrict__ bnb,
                TY* __restrict__ Y, int O)
{
    const int tid = threadIdx.x;
    const int wv = tid >> 6, lane = tid & 63, li = lane & 15, quad = lane >> 4;
    const int wm = wv / WN, wn = wv % WN;
    const int m0 = blockIdx.y * (64 * WM) + wm * 64;
    const int n0 = blockIdx.x * (64 * WN) + wn * 64;
    const int b  = blockIdx.z;
    const bf16* Xb = XT + (size_t)b * S_SP * CIN;

    f32x4 acc[4][4];
    #pragma unroll
    for (int mt = 0; mt < 4; ++mt)
        #pragma unroll
        for (int nt = 0; nt < 4; ++nt) acc[mt][nt] = f32x4{0.f,0.f,0.f,0.f};

    int srow[4];
    #pragma unroll
    for (int nt = 0; nt < 4; ++nt) {
        int s = n0 + nt * 16 + li;
        srow[nt] = (s < S_SP) ? s : (S_SP - 1);   // clamp tail (stores guarded)
    }

    for (int k0 = 0; k0 < CIN; k0 += 32) {
        bf16x8 a[4], bb[4];
        #pragma unroll
        for (int mt = 0; mt < 4; ++mt)
            a[mt] = *(const bf16x8*)(Wb + (size_t)(m0 + mt * 16 + li) * CIN + k0 + quad * 8);
        #pragma unroll
        for (int nt = 0; nt < 4; ++nt)
            bb[nt] = *(const bf16x8*)(Xb + (size_t)srow[nt] * CIN + k0 + quad * 8);
        #pragma unroll
        for (int mt = 0; mt < 4; ++mt)
            #pragma unroll
            for (int nt = 0; nt < 4; ++nt)
                acc[mt][nt] = __builtin_amdgcn_mfma_f32_16x16x32_bf16(a[mt], bb[nt], acc[mt][nt], 0, 0, 0);
    }

    const float rs = rsqrtf(1.0f + 1e-5f);
    #pragma unroll
    for (int mt = 0; mt < 4; ++mt) {
        #pragma unroll
        for (int r = 0; r < 4; ++r) {
            int o = m0 + mt * 16 + quad * 4 + r;
            float bv = (o < 256) ? (blo ? blo[o] : 0.f) : (bhi ? bhi[o - 256] : 0.f);
            float sc = 1.f, sh = 0.f;
            if (BN_) { sc = bng[o] * rs; sh = bnb[o]; }
            #pragma unroll
            for (int nt = 0; nt < 4; ++nt) {
                int s = n0 + nt * 16 + li;
                if (s >= S_SP) continue;
                float v = acc[mt][nt][r] + bv;
                if (BN_) v = v * sc + sh;
                if (LRELU) v = (v >= 0.f) ? v : 0.2f * v;
                if (!PAD_OUT) {
                    Y[((size_t)b * O + o) * S_SP + s] = (TY)v;
                } else {
                    int rr = s / 56, cc = s % 56;
                    Y[(((size_t)b * O + o) * 58 + rr + 1) * 58 + cc + 1] = (TY)v;
                }
            }
        }
    }
}

// ---------------------------------------------------------------------------
// Fused local+global attention per (b,c). grid 4096 x 256.
// Local: S = Q K^T (pad 56->64), row softmax, O = P V.
// Global: P2[h][k] = softmax_k(gs * GK[h][k]), O += P2 GV.
// Single coalesced write of F[b][c][s].
// ---------------------------------------------------------------------------
__global__ __launch_bounds__(256)
void fused_attn_kernel(const bf16* __restrict__ Q, const bf16* __restrict__ KV,
                       const bf16* __restrict__ GKV, const float* __restrict__ gq,
                       bf16* __restrict__ F)
{
    __shared__ bf16 Qs[64][72], Ks[64][72], Vt[64][72], Ps[64][72];
    const int bc  = blockIdx.x;
    const int b = bc >> 8, c = bc & 255;
    const int tid = threadIdx.x;
    const int wv = tid >> 6, lane = tid & 63, li = lane & 15, quad = lane >> 4;
    const int m0 = wv * 16;

    #pragma unroll
    for (int i = tid; i < 64 * 36; i += 256) {
        ((uint32_t*)Qs)[i] = 0; ((uint32_t*)Ks)[i] = 0;
        ((uint32_t*)Vt)[i] = 0; ((uint32_t*)Ps)[i] = 0;
    }
    __syncthreads();

    const bf16* Qp  = Q   + (size_t)bc * S_SP;
    const bf16* Kp  = KV  + (size_t)(b * 512 + c) * S_SP;
    const bf16* Vp  = KV  + (size_t)(b * 512 + 256 + c) * S_SP;
    const bf16* GKp = GKV + (size_t)(b * 512 + c) * S_SP;
    const bf16* GVp = GKV + (size_t)(b * 512 + 256 + c) * S_SP;

    for (int idx = tid; idx < 392; idx += 256) {   // row-major Q/K loads
        int r = idx / 7, cj = (idx % 7) * 8;
        *(bf16x8*)&Qs[r][cj] = *(const bf16x8*)(Qp + r * 56 + cj);
        *(bf16x8*)&Ks[r][cj] = *(const bf16x8*)(Kp + r * 56 + cj);
    }
    for (int idx = tid; idx < 392; idx += 256) {   // Vt scatter: lanes = consecutive r -> conflict-free
        int r = idx % 56, cj = (idx / 56) * 8;
        bf16x8 vv = *(const bf16x8*)(Vp + r * 56 + cj);
        #pragma unroll
        for (int u = 0; u < 8; ++u) Vt[cj + u][r] = vv[u];
    }
    __syncthreads();

    // ---- local: S = Q K^T ----
    f32x4 sacc[4];
    #pragma unroll
    for (int nt = 0; nt < 4; ++nt) sacc[nt] = f32x4{0.f,0.f,0.f,0.f};
    #pragma unroll
    for (int k0 = 0; k0 < 64; k0 += 32) {
        bf16x8 a = *(const bf16x8*)&Qs[m0 + li][k0 + quad * 8];
        #pragma unroll
        for (int nt = 0; nt < 4; ++nt) {
            bf16x8 bb = *(const bf16x8*)&Ks[nt * 16 + li][k0 + quad * 8];
            sacc[nt] = __builtin_amdgcn_mfma_f32_16x16x32_bf16(a, bb, sacc[nt], 0, 0, 0);
        }
    }
    // row softmax -> Ps
    #pragma unroll
    for (int r = 0; r < 4; ++r) {
        float e[4]; float m = -3e38f;
        #pragma unroll
        for (int nt = 0; nt < 4; ++nt) {
            int v = nt * 16 + li;
            float x = (v < 56) ? sacc[nt][r] * SCALE_V : -3e38f;
            e[nt] = x; m = fmaxf(m, x);
        }
        m = fmaxf(m, __shfl_xor(m, 1)); m = fmaxf(m, __shfl_xor(m, 2));
        m = fmaxf(m, __shfl_xor(m, 4)); m = fmaxf(m, __shfl_xor(m, 8));
        float s = 0.f;
        #pragma unroll
        for (int nt = 0; nt < 4; ++nt) {
            float p = (nt * 16 + li < 56) ? __expf(e[nt] - m) : 0.f;
            e[nt] = p; s += p;
        }
        s += __shfl_xor(s, 1); s += __shfl_xor(s, 2);
        s += __shfl_xor(s, 4); s += __shfl_xor(s, 8);
        float inv = 1.f / s;
        int row = m0 + quad * 4 + r;
        #pragma unroll
        for (int nt = 0; nt < 4; ++nt) Ps[row][nt * 16 + li] = (bf16)(e[nt] * inv);
    }
    __syncthreads();

    // ---- local: O = P V ----
    f32x4 oacc[4];
    #pragma unroll
    for (int nt = 0; nt < 4; ++nt) oacc[nt] = f32x4{0.f,0.f,0.f,0.f};
    #pragma unroll
    for (int k0 = 0; k0 < 64; k0 += 32) {
        bf16x8 a = *(const bf16x8*)&Ps[m0 + li][k0 + quad * 8];
        #pragma unroll
        for (int nt = 0; nt < 4; ++nt) {
            bf16x8 bb = *(const bf16x8*)&Vt[nt * 16 + li][k0 + quad * 8];
            oacc[nt] = __builtin_amdgcn_mfma_f32_16x16x32_bf16(a, bb, oacc[nt], 0, 0, 0);
        }
    }
    __syncthreads();   // done reading Vt/Ps

    // ---- global: reload Vt <- GV^T, Ps <- softmax(gs*GK) ----
    for (int idx = tid; idx < 392; idx += 256) {
        int r = idx % 56, cj = (idx / 56) * 8;
        bf16x8 vv = *(const bf16x8*)(GVp + r * 56 + cj);
        #pragma unroll
        for (int u = 0; u < 8; ++u) Vt[cj + u][r] = vv[u];
    }
    const float gs = gq[bc];
    #pragma unroll
    for (int r = 0; r < 4; ++r) {
        int row = m0 + quad * 4 + r;
        const bf16* gkrow = GKp + row * 56;    // rows 56..63 read garbage (finite), discarded at write
        float e[4]; float m = -3e38f;
        #pragma unroll
        for (int nt = 0; nt < 4; ++nt) {
            int k = nt * 16 + li;
            float x = (k < 56) ? gs * bf2f(gkrow[k]) : -3e38f;
            e[nt] = x; m = fmaxf(m, x);
        }
        m = fmaxf(m, __shfl_xor(m, 1)); m = fmaxf(m, __shfl_xor(m, 2));
        m = fmaxf(m, __shfl_xor(m, 4)); m = fmaxf(m, __shfl_xor(m, 8));
        float s = 0.f;
        #pragma unroll
        for (int nt = 0; nt < 4; ++nt) {
            float p = (nt * 16 + li < 56) ? __expf(e[nt] - m) : 0.f;
            e[nt] = p; s += p;
        }
        s += __shfl_xor(s, 1); s += __shfl_xor(s, 2);
        s += __shfl_xor(s, 4); s += __shfl_xor(s, 8);
        float inv = 1.f / s;
        #pragma unroll
        for (int nt = 0; nt < 4; ++nt) Ps[row][nt * 16 + li] = (bf16)(e[nt] * inv);
    }
    __syncthreads();

    // ---- global: O += P2 GV ----
    #pragma unroll
    for (int k0 = 0; k0 < 64; k0 += 32) {
        bf16x8 a = *(const bf16x8*)&Ps[m0 + li][k0 + quad * 8];
        #pragma unroll
        for (int nt = 0; nt < 4; ++nt) {
            bf16x8 bb = *(const bf16x8*)&Vt[nt * 16 + li][k0 + quad * 8];
            oacc[nt] = __builtin_amdgcn_mfma_f32_16x16x32_bf16(a, bb, oacc[nt], 0, 0, 0);
        }
    }
    bf16* Fp = F + (size_t)bc * S_SP;
    #pragma unroll
    for (int r = 0; r < 4; ++r) {
        int h = m0 + quad * 4 + r;
        #pragma unroll
        for (int nt = 0; nt < 4; ++nt) {
            int w = nt * 16 + li;
            if (h < 56 && w < 56) Fp[h * 56 + w] = (bf16)oacc[nt][r];
        }
    }
}

// ---------------------------------------------------------------------------
__global__ __launch_bounds__(256)
void spatial_mean_kernel(const float* __restrict__ X, float* __restrict__ out)
{
    int bc = blockIdx.x, tid = threadIdx.x;
    const float* p = X + (size_t)bc * S_SP;
    float s = 0.f;
    for (int i = tid; i < S_SP; i += 256) s += p[i];
    for (int off = 32; off; off >>= 1) s += __shfl_down(s, off, 64);
    __shared__ float ws[4];
    if ((tid & 63) == 0) ws[tid >> 6] = s;
    __syncthreads();
    if (tid == 0) out[bc] = (ws[0] + ws[1] + ws[2] + ws[3]) * (1.0f / S_SP);
}

__global__ __launch_bounds__(256)
void gq_kernel(const float* __restrict__ pmean,
               const float* c11w, const float* c11b,
               const float* gaw1, const float* gab1, const float* gag1, const float* gabe1,
               const float* gaw2, const float* gab2, const float* gag2, const float* gabe2,
               float* __restrict__ gq)
{
    __shared__ float pm[256], p2[256], hh[64];
    int b = blockIdx.x, t = threadIdx.x;
    pm[t] = pmean[b * 256 + t];
    __syncthreads();
    float a = c11b[t];
    for (int c = 0; c < 256; ++c) a += c11w[t * 256 + c] * pm[c];
    p2[t] = a;
    __syncthreads();
    const float rs = rsqrtf(1.0f + 1e-5f);
    if (t < 64) {
        float h = gab1[t];
        for (int c = 0; c < 256; ++c) h += gaw1[t * 256 + c] * p2[c];
        h = h * (gag1[t] * rs) + gabe1[t];
        hh[t] = (h >= 0.f) ? h : 0.2f * h;
    }
    __syncthreads();
    float g = gab2[t];
    for (int i = 0; i < 64; ++i) g += gaw2[t * 64 + i] * hh[i];
    g = g * (gag2[t] * rs) + gabe2[t];
    gq[b * 256 + t] = g * SCALE_V;
}

__global__ __launch_bounds__(256)
void fill_out_kernel(float* __restrict__ out, const float* __restrict__ c1b)
{
    int idx = blockIdx.x * 256 + threadIdx.x;
    int o = (idx / 3364) & 255;
    out[idx] = c1b[o];
}

// ---------------------------------------------------------------------------
extern "C" void kernel_launch(void* const* d_in, const int* in_sizes, int n_in,
                              void* d_out, int out_size, void* d_ws, size_t ws_size,
                              hipStream_t stream)
{
    (void)in_sizes; (void)n_in; (void)out_size; (void)ws_size;
    const float* x_s   = (const float*)d_in[0];
    const float* x_fq  = (const float*)d_in[1];
    const float* x_mt  = (const float*)d_in[2];
    const float* la_w1 = (const float*)d_in[3];
    const float* la_b1 = (const float*)d_in[4];
    const float* la_g1 = (const float*)d_in[5];
    const float* la_be1= (const float*)d_in[6];
    const float* la_w2 = (const float*)d_in[7];
    const float* la_b2 = (const float*)d_in[8];
    const float* la_g2 = (const float*)d_in[9];
    const float* la_be2= (const float*)d_in[10];
    const float* lk_w  = (const float*)d_in[11];
    const float* lk_b  = (const float*)d_in[12];
    const float* lv_w  = (const float*)d_in[13];
    const float* ga_w1 = (const float*)d_in[14];
    const float* ga_b1 = (const float*)d_in[15];
    const float* ga_g1 = (const float*)d_in[16];
    const float* ga_be1= (const float*)d_in[17];
    const float* ga_w2 = (const float*)d_in[18];
    const float* ga_b2 = (const float*)d_in[19];
    const float* ga_g2 = (const float*)d_in[20];
    const float* ga_be2= (const float*)d_in[21];
    const float* gk_w  = (const float*)d_in[22];
    const float* gk_b  = (const float*)d_in[23];
    const float* gv_w  = (const float*)d_in[24];
    const float* c11_w = (const float*)d_in[25];
    const float* c11_b = (const float*)d_in[26];
    const float* c1_w  = (const float*)d_in[27];
    const float* c1_b  = (const float*)d_in[28];
    float* out = (float*)d_out;

    char* ws = (char*)d_ws;
    const size_t SZ256 = (size_t)16 * 256 * S_SP * 2;     // 25,690,112
    const size_t SZ512 = (size_t)16 * 512 * S_SP * 2;     // 51,380,224
    const size_t SZ64  = (size_t)16 * 64  * S_SP * 2;     //  6,422,528
    bf16* R_A   = (bf16*)(ws);                            // XTfq -> XTs -> F
    bf16* R_KV  = (bf16*)(ws + SZ256);
    bf16* R_GKV = (bf16*)(ws + SZ256 + SZ512);
    bf16* R_D   = (bf16*)(ws + SZ256 + 2*SZ512);          // Q -> F_T
    bf16* R_Hd  = (bf16*)(ws + 2*SZ256 + 2*SZ512);
    bf16* R_HdT = (bf16*)(ws + 2*SZ256 + 2*SZ512 + SZ64);
    bf16* R_WB  = (bf16*)(ws + 2*SZ256 + 2*SZ512 + 2*SZ64);
    float* pmean = (float*)(ws + 2*SZ256 + 2*SZ512 + 2*SZ64 + 1048576);
    float* gqv   = pmean + 16 * 256;

    const bf16* W_la1 = R_WB;
    const bf16* W_la2 = R_WB + 16384;
    const bf16* W_kv  = R_WB + 32768;
    const bf16* W_gkv = R_WB + 163840;
    const bf16* W_c1  = R_WB + 294912;

    dim3 blk(256);

    fill_out_kernel<<<dim3(53824), blk, 0, stream>>>(out, c1_b);
    wprep_kernel<<<dim3(256, 7), blk, 0, stream>>>(la_w1, la_w2, lk_w, lv_w,
                                                   gk_w, gv_w, c1_w, R_WB);

    // ---- global branch K/V (uses R_A as XTfq, freed afterwards) ----
    transpose_kernel<float><<<dim3(49, 4, 16), blk, 0, stream>>>(x_fq, R_A, 256);
    conv_nolds<256,2,2,false,false,false,bf16><<<dim3(25, 4, 16), blk, 0, stream>>>(
        R_A, W_gkv, gk_b, nullptr, nullptr, nullptr, R_GKV, 512);

    // ---- local branch (R_A now holds XTs) ----
    transpose_kernel<float><<<dim3(49, 4, 16), blk, 0, stream>>>(x_s, R_A, 256);
    conv_nolds<256,1,4,true,true,false,bf16><<<dim3(13, 1, 16), blk, 0, stream>>>(
        R_A, W_la1, la_b1, nullptr, la_g1, la_be1, R_Hd, 64);
    transpose_kernel<bf16><<<dim3(49, 1, 16), blk, 0, stream>>>(R_Hd, R_HdT, 64);
    conv_nolds<64,2,2,false,true,false,bf16><<<dim3(25, 2, 16), blk, 0, stream>>>(
        R_HdT, W_la2, la_b2, nullptr, la_g2, la_be2, R_D, 256);
    conv_nolds<256,2,2,false,false,false,bf16><<<dim3(25, 4, 16), blk, 0, stream>>>(
        R_A, W_kv, lk_b, nullptr, nullptr, nullptr, R_KV, 512);

    // ---- global q scalar chain ----
    spatial_mean_kernel<<<dim3(4096), blk, 0, stream>>>(x_mt, pmean);
    gq_kernel<<<dim3(16), blk, 0, stream>>>(pmean, c11_w, c11_b,
        ga_w1, ga_b1, ga_g1, ga_be1, ga_w2, ga_b2, ga_g2, ga_be2, gqv);

    // ---- fused attention (writes F into R_A; convs all done) ----
    fused_attn_kernel<<<dim3(4096), blk, 0, stream>>>(R_D, R_KV, R_GKV, gqv, R_A);

    // ---- F -> F_T (into R_D; Q dead), final conv ----
    transpose_kernel<bf16><<<dim3(49, 4, 16), blk, 0, stream>>>(R_A, R_D, 256);
    conv_nolds<256,2,2,false,false,true,float><<<dim3(25, 2, 16), blk, 0, stream>>>(
        R_D, W_c1, c1_b, nullptr, nullptr, nullptr, out, 256);
}